// Round 1
// baseline (317.886 us; speedup 1.0000x reference)
//
#include <hip/hip_runtime.h>

typedef __bf16 bf16x8 __attribute__((ext_vector_type(8)));
typedef float f32x4 __attribute__((ext_vector_type(4)));
typedef unsigned int u32;

#define IN_STRIDE 88   // lds input row stride (elems); 176B = 11*16B -> b128-aligned rows
#define IN_ROWS   31   // 16 out rows + 14 halo + 1 zero-pad kh=15 row (real data, A=0 there)
#define IN_COLS   80   // 64 out cols + 14 halo + pads; exactly covers all b128 windows
#define SG  324        // lds_out oc-group stride (f32), 1296B (16B-aligned, bank-spread)
#define SH  20         // lds_out h stride (f32), 80B
#define WAVE_OUT 1312  // per-wave lds_out size (f32)

__device__ __forceinline__ unsigned short f2bf(float f) {
    u32 u = __builtin_bit_cast(u32, f);
    return (unsigned short)((u + 0x7FFFu + ((u >> 16) & 1u)) >> 16);  // RNE
}
__device__ __forceinline__ u32 ordmap(float f) {  // order-preserving float->uint
    u32 u = __builtin_bit_cast(u32, f);
    return (u & 0x80000000u) ? ~u : (u | 0x80000000u);
}
__device__ __forceinline__ float ordunmap(u32 u) {
    u32 b = (u & 0x80000000u) ? (u ^ 0x80000000u) : ~u;
    return __builtin_bit_cast(float, b);
}

// One block: sample n, 16 output rows x 64 output cols, all 16 oc.
// Wave w owns cols [16w, 16w+16). K = 15x15 taps padded to 16x16=256 = 8 MFMA K-steps.
// k = 32*ks + 8*g + j  ->  kh = 2*ks + (g>>1), kw = 8*(g&1) + j   (g = lane>>4)
template <int PASS>
__global__ __launch_bounds__(256) void dynconv(const float* __restrict__ x,
                                               const float* __restrict__ kern,
                                               float* __restrict__ out,
                                               u32* __restrict__ maxbuf) {
    __shared__ __align__(16) unsigned short lds_in[IN_ROWS * IN_STRIDE];

    const int tid  = threadIdx.x;
    const int lane = tid & 63;
    const int wave = tid >> 6;
    const int n  = blockIdx.z;
    const int h0 = blockIdx.y * 16;
    const int c0 = blockIdx.x * 64;

    // ---- stage input tile (channel 0 only), reflect-padded, f32 -> bf16 ----
    const float* xs = x + (size_t)n * (16u * 512u * 512u);
    for (int idx = tid; idx < IN_ROWS * IN_COLS; idx += 256) {
        int rr = idx / IN_COLS;
        int cc = idx - rr * IN_COLS;
        int gr = h0 - 7 + rr; gr = gr < 0 ? -gr : (gr > 511 ? 1022 - gr : gr);
        int gc = c0 - 7 + cc; gc = gc < 0 ? -gc : (gc > 511 ? 1022 - gc : gc);
        lds_in[rr * IN_STRIDE + cc] = f2bf(xs[gr * 512 + gc]);
    }

    // ---- A fragments: kernel weights, zero-padded to 16x16 taps, held in regs ----
    const int oca = lane & 15;
    const int g   = lane >> 4;
    const int g1  = g & 1;
    const int g2  = g >> 1;
    bf16x8 afrag[8];
    const float* kp = kern + ((size_t)n * 16 + oca) * 225;
    #pragma unroll
    for (int ks = 0; ks < 8; ++ks) {
        const int kh = 2 * ks + g2;
        #pragma unroll
        for (int j = 0; j < 8; ++j) {
            const int kwv = 8 * g1 + j;
            float v = 0.f;
            if (kh < 15 && kwv < 15) v = kp[kh * 15 + kwv];
            afrag[ks][j] = (__bf16)v;
        }
    }

    __syncthreads();

    // ---- MFMA main loop ----
    f32x4 acc[16];
    #pragma unroll
    for (int t = 0; t < 16; ++t) acc[t] = f32x4{0.f, 0.f, 0.f, 0.f};

    const int hh = lane & 15;                 // B n-dim: output row offset
    const int colbase = wave * 16 + g1 * 8;   // lane-group kw base folded into address

    #pragma unroll
    for (int ks = 0; ks < 8; ++ks) {
        const int row = hh + 2 * ks + g2;     // input row for this lane's k-slice
        const unsigned short* rp = &lds_in[row * IN_STRIDE + colbase];
        const uint4 R0 = *(const uint4*)(rp);
        const uint4 R1 = *(const uint4*)(rp + 8);
        const uint4 R2 = *(const uint4*)(rp + 16);
        const u32 E[12] = {R0.x, R0.y, R0.z, R0.w, R1.x, R1.y, R1.z, R1.w,
                           R2.x, R2.y, R2.z, R2.w};
        #pragma unroll
        for (int t = 0; t < 16; ++t) {        // 16 w-tiles, shift t is compile-time
            const int xb = t >> 1;
            u32 d0, d1, d2, d3;
            if (t & 1) {
                d0 = __builtin_amdgcn_alignbit(E[xb + 1], E[xb], 16);
                d1 = __builtin_amdgcn_alignbit(E[xb + 2], E[xb + 1], 16);
                d2 = __builtin_amdgcn_alignbit(E[xb + 3], E[xb + 2], 16);
                d3 = __builtin_amdgcn_alignbit(E[xb + 4], E[xb + 3], 16);
            } else {
                d0 = E[xb]; d1 = E[xb + 1]; d2 = E[xb + 2]; d3 = E[xb + 3];
            }
            uint4 dv; dv.x = d0; dv.y = d1; dv.z = d2; dv.w = d3;
            acc[t] = __builtin_amdgcn_mfma_f32_16x16x32_bf16(
                afrag[ks], __builtin_bit_cast(bf16x8, dv), acc[t], 0, 0, 0);
        }
    }

    if constexpr (PASS == 0) {
        // ---- per-sample max ----
        float m = -3.4e38f;
        #pragma unroll
        for (int t = 0; t < 16; ++t)
            #pragma unroll
            for (int r = 0; r < 4; ++r) m = fmaxf(m, acc[t][r]);
        #pragma unroll
        for (int off = 32; off > 0; off >>= 1) m = fmaxf(m, __shfl_xor(m, off, 64));
        if (lane == 0) atomicMax(&maxbuf[n], ordmap(m));
    } else {
        // ---- scale + rearrange through per-wave LDS -> coalesced float4 stores ----
        __shared__ __align__(16) float lds_out[4 * WAVE_OUT];
        const float scale = 1.0f / ordunmap(maxbuf[n]);
        float* ow = &lds_out[wave * WAVE_OUT];
        #pragma unroll
        for (int r = 0; r < 4; ++r) {
            #pragma unroll
            for (int q = 0; q < 4; ++q) {
                f32x4 v;
                v[0] = acc[4 * q + 0][r] * scale;
                v[1] = acc[4 * q + 1][r] * scale;
                v[2] = acc[4 * q + 2][r] * scale;
                v[3] = acc[4 * q + 3][r] * scale;
                *(f32x4*)&ow[g * SG + hh * SH + 4 * q] = v;   // (oc-grp g, row hh, w 4q..)
            }
            const int hr = lane >> 2;
            const int c  = lane & 3;
            #pragma unroll
            for (int j = 0; j < 4; ++j) {                      // oc-group j
                f32x4 v = *(const f32x4*)&ow[j * SG + hr * SH + 4 * c];
                const int oc = 4 * j + r;
                size_t o = (((size_t)(oc * 16 + n)) * 512 + (size_t)(h0 + hr)) * 512
                           + (size_t)(c0 + wave * 16 + 4 * c);
                *(f32x4*)&out[o] = v;
            }
        }
    }
}

extern "C" void kernel_launch(void* const* d_in, const int* in_sizes, int n_in,
                              void* d_out, int out_size, void* d_ws, size_t ws_size,
                              hipStream_t stream) {
    (void)in_sizes; (void)n_in; (void)out_size; (void)ws_size;
    const float* x  = (const float*)d_in[0];
    const float* k  = (const float*)d_in[1];
    float* out      = (float*)d_out;
    u32* maxbuf     = (u32*)d_ws;

    hipMemsetAsync(d_ws, 0, 16 * sizeof(u32), stream);  // ordmap(-inf) == 0

    dim3 grid(8, 32, 16);   // (512/64 col-tiles, 512/16 row-tiles, 16 samples)
    dim3 block(256);
    dynconv<0><<<grid, block, 0, stream>>>(x, k, out, maxbuf);  // max pass
    dynconv<1><<<grid, block, 0, stream>>>(x, k, out, maxbuf);  // write pass
}

// Round 2
// 170.915 us; speedup vs baseline: 1.8599x; 1.8599x over previous
//
#include <hip/hip_runtime.h>

typedef __bf16 bf16x8 __attribute__((ext_vector_type(8)));
typedef float f32x4 __attribute__((ext_vector_type(4)));
typedef unsigned int u32;

#define IN_STRIDE 88   // lds input row stride (elems); 176B = 16B-aligned rows
#define IN_ROWS   31   // 16 out rows + 14 halo + 1 row for kh=15 zero-pad slot (real data, A=0)
#define IN_COLS   80   // cols c0-8 .. c0+71 staged as 20 aligned float4 per row
#define SG  324        // lds_out oc-group stride (f32)
#define SH  20         // lds_out h stride (f32)
#define WAVE_OUT 1312  // per-wave lds_out size (f32)

__device__ __forceinline__ unsigned short f2bf(float f) {
    u32 u = __builtin_bit_cast(u32, f);
    return (unsigned short)((u + 0x7FFFu + ((u >> 16) & 1u)) >> 16);  // RNE
}
__device__ __forceinline__ int refl(int i) {  // reflect index into [0,512)
    return i < 0 ? -i : (i > 511 ? 1022 - i : i);
}

// One block: sample n, 16 output rows x 64 output cols, all 16 oc.
// Wave w owns cols [16w, 16w+16). K = 15x15 taps padded to 16x16=256 = 8 MFMA K-steps.
// k = 32*ks + 8*g + j  ->  kh = 2*ks + (g>>1), kw = 8*(g&1) + j   (g = lane>>4)
template <int PASS>
__global__ __launch_bounds__(256) void dynconv(const float* __restrict__ x,
                                               const float* __restrict__ kern,
                                               float* __restrict__ out,
                                               float* __restrict__ bmax,
                                               const float* __restrict__ maxf) {
    __shared__ __align__(16) unsigned short lds_in[IN_ROWS * IN_STRIDE];
    __shared__ float wm[4];

    const int tid  = threadIdx.x;
    const int lane = tid & 63;
    const int wave = tid >> 6;
    const int n  = blockIdx.z;
    const int h0 = blockIdx.y * 16;
    const int c0 = blockIdx.x * 64;

    // ---- stage input tile (channel 0 only), reflect-padded, f32 -> bf16 ----
    // cols [c0-8, c0+72): 20 float4 slots per row; rows h0-7 .. h0+23 (reflected)
    const float* xs = x + (size_t)n * (16u * 512u * 512u);
    {
        const int cs = tid & 31;   // col slot (active < 20)
        const int r0 = tid >> 5;   // row 0..7, step 8
        if (cs < 20) {
            #pragma unroll
            for (int i = 0; i < 4; ++i) {
                const int rr = r0 + 8 * i;
                if (rr < IN_ROWS) {
                    const float* rowp = xs + refl(h0 - 7 + rr) * 512;
                    const int gc0 = c0 - 8 + 4 * cs;
                    float v0, v1, v2, v3;
                    if (gc0 >= 0 && gc0 <= 508) {           // aligned interior fast path
                        const float4 v = *(const float4*)(rowp + gc0);
                        v0 = v.x; v1 = v.y; v2 = v.z; v3 = v.w;
                    } else {                                // border reflect, scalar
                        v0 = rowp[refl(gc0)];
                        v1 = rowp[refl(gc0 + 1)];
                        v2 = rowp[refl(gc0 + 2)];
                        v3 = rowp[refl(gc0 + 3)];
                    }
                    const u32 lo = (u32)f2bf(v0) | ((u32)f2bf(v1) << 16);
                    const u32 hi = (u32)f2bf(v2) | ((u32)f2bf(v3) << 16);
                    *(uint2*)&lds_in[rr * IN_STRIDE + 4 * cs] = make_uint2(lo, hi);
                }
            }
        }
    }

    // ---- A fragments: kernel weights, zero-padded to 16x16 taps, in regs ----
    const int oca = lane & 15;
    const int g   = lane >> 4;
    const int g1  = g & 1;
    const int g2  = g >> 1;
    bf16x8 afrag[8];
    const float* kp = kern + ((size_t)n * 16 + oca) * 225;
    #pragma unroll
    for (int ks = 0; ks < 8; ++ks) {
        const int kh = 2 * ks + g2;
        #pragma unroll
        for (int j = 0; j < 8; ++j) {
            const int kwv = 8 * g1 + j;
            float v = 0.f;
            if (kh < 15 && kwv < 15) v = kp[kh * 15 + kwv];
            afrag[ks][j] = (__bf16)v;
        }
    }

    __syncthreads();

    // ---- MFMA main loop ----
    f32x4 acc[16];
    #pragma unroll
    for (int t = 0; t < 16; ++t) acc[t] = f32x4{0.f, 0.f, 0.f, 0.f};

    const int hh = lane & 15;                 // B n-dim: output row offset
    const int colbase = wave * 16 + g1 * 8;   // even -> 16B-aligned b128 reads

    #pragma unroll
    for (int ks = 0; ks < 8; ++ks) {
        const int row = hh + 2 * ks + g2;     // input row for this lane's k-slice
        const unsigned short* rp = &lds_in[row * IN_STRIDE + colbase];
        const uint4 R0 = *(const uint4*)(rp);
        const uint4 R1 = *(const uint4*)(rp + 8);
        const uint4 R2 = *(const uint4*)(rp + 16);
        const u32 E[12] = {R0.x, R0.y, R0.z, R0.w, R1.x, R1.y, R1.z, R1.w,
                           R2.x, R2.y, R2.z, R2.w};
        #pragma unroll
        for (int t = 0; t < 16; ++t) {        // window shift s = t+1 (staging at c0-8)
            const int s  = t + 1;
            const int xb = s >> 1;
            u32 d0, d1, d2, d3;
            if (s & 1) {
                d0 = __builtin_amdgcn_alignbit(E[xb + 1], E[xb], 16);
                d1 = __builtin_amdgcn_alignbit(E[xb + 2], E[xb + 1], 16);
                d2 = __builtin_amdgcn_alignbit(E[xb + 3], E[xb + 2], 16);
                d3 = __builtin_amdgcn_alignbit(E[xb + 4], E[xb + 3], 16);
            } else {
                d0 = E[xb]; d1 = E[xb + 1]; d2 = E[xb + 2]; d3 = E[xb + 3];
            }
            uint4 dv; dv.x = d0; dv.y = d1; dv.z = d2; dv.w = d3;
            acc[t] = __builtin_amdgcn_mfma_f32_16x16x32_bf16(
                afrag[ks], __builtin_bit_cast(bf16x8, dv), acc[t], 0, 0, 0);
        }
    }

    if constexpr (PASS == 0) {
        // ---- per-block max -> one plain store (no atomics) ----
        float m = -3.4e38f;
        #pragma unroll
        for (int t = 0; t < 16; ++t)
            #pragma unroll
            for (int r = 0; r < 4; ++r) m = fmaxf(m, acc[t][r]);
        #pragma unroll
        for (int off = 32; off > 0; off >>= 1) m = fmaxf(m, __shfl_xor(m, off, 64));
        if (lane == 0) wm[wave] = m;
        __syncthreads();
        if (tid == 0)
            bmax[n * 256 + blockIdx.y * 8 + blockIdx.x] =
                fmaxf(fmaxf(wm[0], wm[1]), fmaxf(wm[2], wm[3]));
    } else {
        // ---- scale + rearrange through per-wave LDS -> coalesced float4 stores ----
        __shared__ __align__(16) float lds_out[4 * WAVE_OUT];
        const float scale = 1.0f / maxf[n];
        float* ow = &lds_out[wave * WAVE_OUT];
        #pragma unroll
        for (int r = 0; r < 4; ++r) {
            #pragma unroll
            for (int q = 0; q < 4; ++q) {
                f32x4 v;
                v[0] = acc[4 * q + 0][r] * scale;
                v[1] = acc[4 * q + 1][r] * scale;
                v[2] = acc[4 * q + 2][r] * scale;
                v[3] = acc[4 * q + 3][r] * scale;
                *(f32x4*)&ow[g * SG + hh * SH + 4 * q] = v;   // (oc-grp g, row hh, w 4q..)
            }
            const int hr = lane >> 2;
            const int c  = lane & 3;
            #pragma unroll
            for (int j = 0; j < 4; ++j) {                      // oc-group j
                f32x4 v = *(const f32x4*)&ow[j * SG + hr * SH + 4 * c];
                const int oc = 4 * j + r;
                size_t o = (((size_t)(oc * 16 + n)) * 512 + (size_t)(h0 + hr)) * 512
                           + (size_t)(c0 + wave * 16 + 4 * c);
                *(f32x4*)&out[o] = v;
            }
        }
    }
}

// 16 blocks: reduce 256 per-block maxima -> maxf[n]
__global__ __launch_bounds__(256) void reducemax(const float* __restrict__ bmax,
                                                 float* __restrict__ maxf) {
    const int n = blockIdx.x;
    float v = bmax[n * 256 + threadIdx.x];
    #pragma unroll
    for (int off = 32; off > 0; off >>= 1) v = fmaxf(v, __shfl_xor(v, off, 64));
    __shared__ float wm[4];
    if ((threadIdx.x & 63) == 0) wm[threadIdx.x >> 6] = v;
    __syncthreads();
    if (threadIdx.x == 0)
        maxf[n] = fmaxf(fmaxf(wm[0], wm[1]), fmaxf(wm[2], wm[3]));
}

extern "C" void kernel_launch(void* const* d_in, const int* in_sizes, int n_in,
                              void* d_out, int out_size, void* d_ws, size_t ws_size,
                              hipStream_t stream) {
    (void)in_sizes; (void)n_in; (void)out_size; (void)ws_size;
    const float* x  = (const float*)d_in[0];
    const float* k  = (const float*)d_in[1];
    float* out      = (float*)d_out;
    float* bmax     = (float*)d_ws;          // 16*256 floats
    float* maxf     = bmax + 16 * 256;       // 16 floats

    dim3 grid(8, 32, 16);   // (512/64 col-tiles, 512/16 row-tiles, 16 samples)
    dim3 block(256);
    dynconv<0><<<grid, block, 0, stream>>>(x, k, out, bmax, maxf);  // max pass
    reducemax<<<dim3(16), block, 0, stream>>>(bmax, maxf);          // 16 maxima
    dynconv<1><<<grid, block, 0, stream>>>(x, k, out, bmax, maxf);  // write pass
}